// Round 11
// baseline (1068.614 us; speedup 1.0000x reference)
//
#include <hip/hip_runtime.h>

#define D_G   512
#define D_H   1024
#define D_OUT 512
#define BATCH 64
#define LAMv  0.95f
#define ETAv  0.5f

// ---------------------------------------------------------------------------
// ws layout (floats):
//   zg   : 16 * 65536   hfin: 65536   predp: 16 * 32768   bvals: 128
//   WhT  : 1024*1024    WgT : 512*1024   hWT: 1024*512
// 6 dispatches total: tr3, zg, recur, head, loss_b, final.
// ---------------------------------------------------------------------------

__device__ inline float4 f4fma(float4 w, float s, float4 a) {
  a.x = fmaf(w.x, s, a.x); a.y = fmaf(w.y, s, a.y);
  a.z = fmaf(w.z, s, a.z); a.w = fmaf(w.w, s, a.w);
  return a;
}

// wave-wide sum; result valid in lane 0
__device__ inline float wred(float x) {
#pragma unroll
  for (int off = 32; off > 0; off >>= 1) x += __shfl_down(x, off);
  return x;
}

// all three weight transposes in ONE dispatch. flat 512 blocks.
__global__ __launch_bounds__(256) void k_tr3(const float* __restrict__ Wh,
                                             const float* __restrict__ Wg,
                                             const float* __restrict__ hW,
                                             float* __restrict__ WhT,
                                             float* __restrict__ WgT,
                                             float* __restrict__ hWT) {
  __shared__ float t[64][65];
  const int id = blockIdx.x;
  const float* src; float* dst; int R, C, bx, by;
  if (id < 256)      { src = Wh; dst = WhT; R = 1024; C = 1024;
                       bx = id & 15;        by = id >> 4; }
  else if (id < 384) { src = Wg; dst = WgT; R = 1024; C = 512;
                       bx = (id-256) & 7;   by = (id-256) >> 3; }
  else               { src = hW; dst = hWT; R = 512;  C = 1024;
                       bx = (id-384) & 15;  by = (id-384) >> 4; }
  const int c0 = bx * 64, r0 = by * 64;
  const int tid = threadIdx.x;
  const int lr = tid >> 4;
  const int lc = (tid & 15) * 4;
#pragma unroll
  for (int p = 0; p < 4; ++p) {
    int r = lr + p * 16;
    float4 v = *(const float4*)&src[(size_t)(r0 + r) * C + c0 + lc];
    t[r][lc] = v.x; t[r][lc+1] = v.y; t[r][lc+2] = v.z; t[r][lc+3] = v.w;
  }
  __syncthreads();
#pragma unroll
  for (int p = 0; p < 4; ++p) {
    int c = lr + p * 16;
    float4 v = make_float4(t[lc][c], t[lc+1][c], t[lc+2][c], t[lc+3][c]);
    *(float4*)&dst[(size_t)(c0 + c) * R + r0 + lc] = v;
  }
}

// zg[t][b][i] = z[t][b][:].Wg[i][:] + bh[i]  (input-only, full machine)
__global__ __launch_bounds__(256) void k_zg(const float* __restrict__ z,
                                            const float* __restrict__ WgT,
                                            const float* __restrict__ bh,
                                            float* __restrict__ zg) {
  const int lane = threadIdx.x & 63;
  const int wid  = __builtin_amdgcn_readfirstlane(threadIdx.x >> 6);
  const int iq   = blockIdx.x * 64 + lane;
  const int b0   = blockIdx.y * 8 + wid * 2;
  const int t    = blockIdx.z;
  const float4* w4  = (const float4*)WgT;
  const float4* zr0 = (const float4*)(z + ((size_t)t * BATCH + b0) * D_G);
  const float4* zr1 = (const float4*)(z + ((size_t)t * BATCH + b0 + 1) * D_G);
  float4 A0 = {0,0,0,0}, A1 = {0,0,0,0};
#pragma unroll 2
  for (int jq = 0; jq < D_G / 4; ++jq) {
    float4 zv0 = zr0[jq], zv1 = zr1[jq];
    float4 wa = w4[(size_t)jq*1024 +       iq];
    float4 wb = w4[(size_t)jq*1024 + 256 + iq];
    float4 wc = w4[(size_t)jq*1024 + 512 + iq];
    float4 wd = w4[(size_t)jq*1024 + 768 + iq];
    A0 = f4fma(wa, zv0.x, A0); A0 = f4fma(wb, zv0.y, A0);
    A0 = f4fma(wc, zv0.z, A0); A0 = f4fma(wd, zv0.w, A0);
    A1 = f4fma(wa, zv1.x, A1); A1 = f4fma(wb, zv1.y, A1);
    A1 = f4fma(wc, zv1.z, A1); A1 = f4fma(wd, zv1.w, A1);
  }
  float4 bias = ((const float4*)bh)[iq];
  A0.x += bias.x; A0.y += bias.y; A0.z += bias.z; A0.w += bias.w;
  A1.x += bias.x; A1.y += bias.y; A1.z += bias.z; A1.w += bias.w;
  float4* o = (float4*)(zg + (size_t)t * (BATCH * D_H));
  o[(size_t)b0 * 256 + iq] = A0;
  o[(size_t)(b0 + 1) * 256 + iq] = A1;
}

// hb += h_prev @ Wh^T, replicating k_hbase's 16-partial k-split order
// (partials P_k accumulated j-ascending, then hb += P_k for k = 0..15).
__device__ inline float4 matvec_wh(float4 hb, const float* __restrict__ hp,
                                   const float4* __restrict__ w4, int tid) {
#pragma unroll 1
  for (int k = 0; k < 16; ++k) {
    float4 P = {0.f, 0.f, 0.f, 0.f};
    const int jq0 = k * 16;
#pragma unroll
    for (int jq = jq0; jq < jq0 + 16; ++jq) {
      float4 hv = ((const float4*)hp)[jq];         // LDS broadcast
      float4 wa = w4[(size_t)jq*1024 +       tid];
      float4 wb = w4[(size_t)jq*1024 + 256 + tid];
      float4 wc = w4[(size_t)jq*1024 + 512 + tid];
      float4 wd = w4[(size_t)jq*1024 + 768 + tid];
      P = f4fma(wa, hv.x, P); P = f4fma(wb, hv.y, P);
      P = f4fma(wc, hv.z, P); P = f4fma(wd, hv.w, P);
    }
    hb.x += P.x; hb.y += P.y; hb.z += P.z; hb.w += P.w;
  }
  return hb;
}

// THE ENTIRE RECURRENCE in one launch: 64 blocks (one per batch), 256 thr.
// History h_0..h_14 lives in LDS (60 KB); h never round-trips to global.
// All arithmetic orders replicate the R9 multi-kernel version.
__global__ __launch_bounds__(256) void k_recur(
    const float* __restrict__ zg, const float* __restrict__ WhT,
    const float* __restrict__ gamma, const float* __restrict__ beta,
    const float* __restrict__ alphap, float* __restrict__ hfin) {
  __shared__ float lh[15][D_H];         // history rows (gated steps 0..14)
  __shared__ float red[2][64];          // parity-alternated reduce scratch
  __shared__ float lamp[16];            // ETA * LAM^m, multiply-chain exact
  const int tid = threadIdx.x;
  const int b   = blockIdx.x;
  const int lane = tid & 63, w = tid >> 6;
  const float4* w4 = (const float4*)WhT;
  float4* lh4 = (float4*)lh;

  if (tid == 0) {
    float v = ETAv;
    lamp[0] = v;
#pragma unroll
    for (int m = 1; m < 15; ++m) { v *= LAMv; lamp[m] = v; }
  }
  const float4 gi = ((const float4*)gamma)[tid];
  const float4 bi = ((const float4*)beta)[tid];
  const float al = alphap[0];
  const float kk = (al >= 0.f) ? (1.f + log1pf(expf(al)))
                               : (1.f / (1.f + log1pf(expf(-al))));
  float4 hc;

  // ---------------- gated timesteps t = 0..14 ----------------
#pragma unroll 1
  for (int t = 0; t < 15; ++t) {
    __syncthreads();                    // lh[t-1] + lamp visible; red reusable
    float4 hb = ((const float4*)zg)[((size_t)t * BATCH + b) * 256 + tid];
    if (t > 0) hb = matvec_wh(hb, lh[t - 1], w4, tid);

    // pre-reduce: Shb, Shb2
    {
      float r0 = wred((hb.x + hb.y) + (hb.z + hb.w));
      float r1 = wred((hb.x*hb.x + hb.y*hb.y) + (hb.z*hb.z + hb.w*hb.w));
      if (lane == 0) { red[0][w] = r0; red[0][4 + w] = r1; }
    }
    __syncthreads();
    const float Shb  = (red[0][0] + red[0][1]) + (red[0][2] + red[0][3]);
    const float Shb2 = (red[0][4] + red[0][5]) + (red[0][6] + red[0][7]);
    float mu  = Shb * (1.f / D_H);
    float var = Shb2 * (1.f / D_H) - mu * mu;
    float rs  = rsqrtf(var + 1e-5f);
    hc.x = fmaxf(0.f, (hb.x - mu) * rs * gi.x + bi.x);
    hc.y = fmaxf(0.f, (hb.y - mu) * rs * gi.y + bi.y);
    hc.z = fmaxf(0.f, (hb.z - mu) * rs * gi.z + bi.z);
    hc.w = fmaxf(0.f, (hb.w - mu) * rs * gi.w + bi.w);

    if (t > 0) {
#pragma unroll 1
      for (int r = 0; r < 3; ++r) {
        // d_s = h . h_s  (scalar per s; no runtime-indexed reg arrays)
        for (int s = 0; s < t; ++s) {
          float4 lv = lh4[s * 256 + tid];
          float p = (hc.x*lv.x + hc.y*lv.y) + (hc.z*lv.z + hc.w*lv.w);
          p = wred(p);
          if (lane == 0) red[1][s * 4 + w] = p;
        }
        __syncthreads();
        // ah ascending, coef = lamp[t-1-s] * ds
        float4 ah = {0.f, 0.f, 0.f, 0.f};
        for (int s = 0; s < t; ++s) {
          float ds = (red[1][s*4] + red[1][s*4+1])
                   + (red[1][s*4+2] + red[1][s*4+3]);
          float coef = lamp[t - 1 - s] * ds;
          float4 lv = lh4[s * 256 + tid];
          ah.x = fmaf(coef, lv.x, ah.x); ah.y = fmaf(coef, lv.y, ah.y);
          ah.z = fmaf(coef, lv.z, ah.z); ah.w = fmaf(coef, lv.w, ah.w);
        }
        // single 5-value reduction
        {
          float q0 = wred((hc.x*ah.x + hc.y*ah.y) + (hc.z*ah.z + hc.w*ah.w));
          float q1 = wred((hc.x*hc.x + hc.y*hc.y) + (hc.z*hc.z + hc.w*hc.w));
          float q2 = wred((ah.x*ah.x + ah.y*ah.y) + (ah.z*ah.z + ah.w*ah.w));
          float q3 = wred((hb.x*ah.x + hb.y*ah.y) + (hb.z*ah.z + hb.w*ah.w));
          float q4 = wred((ah.x + ah.y) + (ah.z + ah.w));
          if (lane == 0) {
            red[0][w] = q0; red[0][4+w] = q1; red[0][8+w] = q2;
            red[0][12+w] = q3; red[0][16+w] = q4;
          }
        }
        __syncthreads();
        float S_hAh  = (red[0][0]+red[0][1])+(red[0][2]+red[0][3]);
        float S_h2   = (red[0][4]+red[0][5])+(red[0][6]+red[0][7]);
        float S_Ah2  = (red[0][8]+red[0][9])+(red[0][10]+red[0][11]);
        float S_hbAh = (red[0][12]+red[0][13])+(red[0][14]+red[0][15]);
        float S_ah   = (red[0][16]+red[0][17])+(red[0][18]+red[0][19]);
        float n1 = sqrtf(S_h2) + 1e-6f;
        float n2 = sqrtf(S_Ah2) + 1e-6f;
        float R  = S_hAh / (n1 * n2 + 1e-6f);
        float Rp = fminf(fmaxf(R, 0.f), 1.f);
        float ad = 1.f - powf(1.f - Rp, kk);
        float oma = 1.f - ad * ad;
        float4 hn;
        hn.x = oma*hb.x + ad*ah.x; hn.y = oma*hb.y + ad*ah.y;
        hn.z = oma*hb.z + ad*ah.z; hn.w = oma*hb.w + ad*ah.w;
        float Shn  = oma * Shb + ad * S_ah;
        float Shn2 = oma*oma*Shb2 + 2.f*oma*ad*S_hbAh + ad*ad*S_Ah2;
        float mu2  = Shn * (1.f / D_H);
        float var2 = Shn2 * (1.f / D_H) - mu2 * mu2;
        float rs2  = rsqrtf(var2 + 1e-5f);
        hc.x = fmaxf(0.f, (hn.x - mu2) * rs2 * gi.x + bi.x);
        hc.y = fmaxf(0.f, (hn.y - mu2) * rs2 * gi.y + bi.y);
        hc.z = fmaxf(0.f, (hn.z - mu2) * rs2 * gi.z + bi.z);
        hc.w = fmaxf(0.f, (hn.w - mu2) * rs2 * gi.w + bi.w);
        if (r < 2) __syncthreads();     // red[1] reuse in next r
      }
    }
    lh4[t * 256 + tid] = hc;            // history row t (= h for next step)
  }

  // ---------------- final timestep t = 15 (no gating) ----------------
  __syncthreads();                      // lh[14] visible
  float4 hb = ((const float4*)zg)[((size_t)15 * BATCH + b) * 256 + tid];
  hb = matvec_wh(hb, lh[14], w4, tid);
  {
    float r0 = wred((hb.x + hb.y) + (hb.z + hb.w));
    float r1 = wred((hb.x*hb.x + hb.y*hb.y) + (hb.z*hb.z + hb.w*hb.w));
    if (lane == 0) { red[0][w] = r0; red[0][4 + w] = r1; }
  }
  __syncthreads();
  const float Shb  = (red[0][0] + red[0][1]) + (red[0][2] + red[0][3]);
  const float Shb2 = (red[0][4] + red[0][5]) + (red[0][6] + red[0][7]);
  float mu  = Shb * (1.f / D_H);
  float var = Shb2 * (1.f / D_H) - mu * mu;
  float rs  = rsqrtf(var + 1e-5f);
  hc.x = fmaxf(0.f, (hb.x - mu) * rs * gi.x + bi.x);
  hc.y = fmaxf(0.f, (hb.y - mu) * rs * gi.y + bi.y);
  hc.z = fmaxf(0.f, (hb.z - mu) * rs * gi.z + bi.z);
  hc.w = fmaxf(0.f, (hb.w - mu) * rs * gi.w + bi.w);
#pragma unroll 1
  for (int r = 0; r < 3; ++r) {
    for (int s = 0; s < 15; ++s) {
      float4 lv = lh4[s * 256 + tid];
      float p = (hc.x*lv.x + hc.y*lv.y) + (hc.z*lv.z + hc.w*lv.w);
      p = wred(p);
      if (lane == 0) red[1][s * 4 + w] = p;
    }
    __syncthreads();
    float4 ah = {0.f, 0.f, 0.f, 0.f};
    for (int s = 0; s < 15; ++s) {
      float ds = (red[1][s*4] + red[1][s*4+1])
               + (red[1][s*4+2] + red[1][s*4+3]);
      float coef = lamp[14 - s] * ds;
      float4 lv = lh4[s * 256 + tid];
      ah.x = fmaf(coef, lv.x, ah.x); ah.y = fmaf(coef, lv.y, ah.y);
      ah.z = fmaf(coef, lv.z, ah.z); ah.w = fmaf(coef, lv.w, ah.w);
    }
    {
      float q0 = wred((hb.x*ah.x + hb.y*ah.y) + (hb.z*ah.z + hb.w*ah.w));
      float q1 = wred((ah.x*ah.x + ah.y*ah.y) + (ah.z*ah.z + ah.w*ah.w));
      float q2 = wred((ah.x + ah.y) + (ah.z + ah.w));
      if (lane == 0) { red[0][w] = q0; red[0][4+w] = q1; red[0][8+w] = q2; }
    }
    __syncthreads();
    float S_hbAh = (red[0][0]+red[0][1])+(red[0][2]+red[0][3]);
    float S_Ah2  = (red[0][4]+red[0][5])+(red[0][6]+red[0][7]);
    float S_ah   = (red[0][8]+red[0][9])+(red[0][10]+red[0][11]);
    float4 hn;
    hn.x = hb.x + ah.x; hn.y = hb.y + ah.y;
    hn.z = hb.z + ah.z; hn.w = hb.w + ah.w;
    float Shn  = Shb + S_ah;
    float Shn2 = Shb2 + 2.f * S_hbAh + S_Ah2;
    float mu2  = Shn * (1.f / D_H);
    float var2 = Shn2 * (1.f / D_H) - mu2 * mu2;
    float rs2  = rsqrtf(var2 + 1e-5f);
    hc.x = fmaxf(0.f, (hn.x - mu2) * rs2 * gi.x + bi.x);
    hc.y = fmaxf(0.f, (hn.y - mu2) * rs2 * gi.y + bi.y);
    hc.z = fmaxf(0.f, (hn.z - mu2) * rs2 * gi.z + bi.z);
    hc.w = fmaxf(0.f, (hn.w - mu2) * rs2 * gi.w + bi.w);
    if (r < 2) __syncthreads();
  }
  ((float4*)(hfin + (size_t)b * D_H))[tid] = hc;
}

// Partial head via hWT. grid (2 oq, 8 by, 16 k), 256 thr.
__global__ __launch_bounds__(256) void k_head(const float* __restrict__ hfin,
                                              const float* __restrict__ hWT,
                                              float* __restrict__ predp) {
  const int lane = threadIdx.x & 63;
  const int wid  = __builtin_amdgcn_readfirstlane(threadIdx.x >> 6);
  const int oq   = blockIdx.x * 64 + lane;
  const int b0   = blockIdx.y * 8 + wid * 2;
  const int k    = blockIdx.z;
  const float4* w4 = (const float4*)hWT;
  const float4* h0 = (const float4*)(hfin + (size_t)b0 * D_H);
  const float4* h1 = (const float4*)(hfin + (size_t)(b0 + 1) * D_H);
  float4 A0 = {0,0,0,0}, A1 = {0,0,0,0};
  const int jq0 = k * 16;
#pragma unroll 2
  for (int jq = jq0; jq < jq0 + 16; ++jq) {
    float4 hv0 = h0[jq], hv1 = h1[jq];
    float4 wa = w4[(size_t)jq*512 +       oq];
    float4 wb = w4[(size_t)jq*512 + 128 + oq];
    float4 wc = w4[(size_t)jq*512 + 256 + oq];
    float4 wd = w4[(size_t)jq*512 + 384 + oq];
    A0 = f4fma(wa, hv0.x, A0); A0 = f4fma(wb, hv0.y, A0);
    A0 = f4fma(wc, hv0.z, A0); A0 = f4fma(wd, hv0.w, A0);
    A1 = f4fma(wa, hv1.x, A1); A1 = f4fma(wb, hv1.y, A1);
    A1 = f4fma(wc, hv1.z, A1); A1 = f4fma(wd, hv1.w, A1);
  }
  float4* o = (float4*)(predp + (size_t)k * (BATCH * D_OUT));
  o[(size_t)b0 * 128 + oq] = A0;
  o[(size_t)(b0 + 1) * 128 + oq] = A1;
}

// per-batch loss terms; one block per batch.
__global__ __launch_bounds__(256) void k_loss_b(
    const float* __restrict__ predp, const float* __restrict__ hbias,
    const float* __restrict__ clean, float* __restrict__ bvals) {
  __shared__ float red[16];
  const int b = blockIdx.x;
  const int tid = threadIdx.x;
  const int lane = tid & 63, w = tid >> 6;
  float sd = 0, sc = 0, spc = 0, sp = 0;
#pragma unroll
  for (int e = 0; e < 2; ++e) {
    const int o = e * 256 + tid;
    const size_t idx = (size_t)b * D_OUT + o;
    float p = hbias[o];
#pragma unroll
    for (int k = 0; k < 16; ++k) p += predp[idx + (size_t)k * 32768];
    float c = clean[idx];
    float d = p - c;
    sd = fmaf(d, d, sd); sc = fmaf(c, c, sc);
    spc = fmaf(p, c, spc); sp = fmaf(p, p, sp);
  }
  sd = wred(sd); sc = wred(sc); spc = wred(spc); sp = wred(sp);
  if (lane == 0) {
    red[w] = sd; red[4 + w] = sc; red[8 + w] = spc; red[12 + w] = sp;
  }
  __syncthreads();
  if (tid == 0) {
    float Sd  = (red[0] + red[1]) + (red[2] + red[3]);
    float Sc  = (red[4] + red[5]) + (red[6] + red[7]);
    float Spc = (red[8] + red[9]) + (red[10] + red[11]);
    float Sp  = (red[12] + red[13]) + (red[14] + red[15]);
    bvals[b * 2 + 0] = Sd / (Sc + 1e-6f);
    bvals[b * 2 + 1] = Spc / ((sqrtf(Sp) + 1e-6f) * (sqrtf(Sc) + 1e-6f));
  }
}

__global__ __launch_bounds__(64) void k_final(const float* __restrict__ bvals,
                                              float* __restrict__ out) {
  const int tid = threadIdx.x;
  float l = bvals[tid * 2 + 0];
  float a = bvals[tid * 2 + 1];
  l = wred(l); a = wred(a);
  if (tid == 0) { out[0] = l * (1.f / BATCH); out[1] = a * (1.f / BATCH); }
}

extern "C" void kernel_launch(void* const* d_in, const int* in_sizes, int n_in,
                              void* d_out, int out_size, void* d_ws, size_t ws_size,
                              hipStream_t stream) {
  (void)in_sizes; (void)n_in; (void)out_size; (void)ws_size;
  const float* z     = (const float*)d_in[0];   // [16][64][512]
  const float* clean = (const float*)d_in[1];   // [64][512]
  const float* Wh    = (const float*)d_in[2];   // [1024][1024]
  const float* Wg    = (const float*)d_in[3];   // [1024][512]
  const float* bh    = (const float*)d_in[4];   // [1024]
  const float* gam   = (const float*)d_in[5];   // [1024]
  const float* bet   = (const float*)d_in[6];   // [1024]
  const float* alp   = (const float*)d_in[7];   // [1]
  const float* hW    = (const float*)d_in[8];   // [512][1024]
  const float* hbias = (const float*)d_in[9];   // [512]

  float* ws    = (float*)d_ws;
  float* zg    = ws;                          // 16*65536
  float* hfin  = zg + 16 * 65536;             // 65536
  float* predp = hfin + 65536;                // 16*32768
  float* bvals = predp + 16 * 32768;          // 128
  float* WhT   = bvals + 128;                 // 1024*1024
  float* WgT   = WhT + 1024 * 1024;           // 512*1024
  float* hWT   = WgT + 512 * 1024;            // 1024*512

  k_tr3<<<dim3(512), dim3(256), 0, stream>>>(Wh, Wg, hW, WhT, WgT, hWT);
  k_zg<<<dim3(4, 8, 16), dim3(256), 0, stream>>>(z, WgT, bh, zg);
  k_recur<<<dim3(64), dim3(256), 0, stream>>>(zg, WhT, gam, bet, alp, hfin);
  k_head<<<dim3(2, 8, 16), dim3(256), 0, stream>>>(hfin, hWT, predp);
  k_loss_b<<<dim3(64), dim3(256), 0, stream>>>(predp, hbias, clean, bvals);
  k_final<<<dim3(1), dim3(64), 0, stream>>>(bvals, (float*)d_out);
}